// Round 3
// baseline (730.401 us; speedup 1.0000x reference)
//
#include <hip/hip_runtime.h>
#include <hip/hip_bf16.h>

#define MINV 1e-15f
#define MAXNRM 0.996f   // (1 - PROJ_EPS)/sqrt(c), c=1, PROJ_EPS=0.004

// butterfly sum over 64 lanes; every lane ends with the total
__device__ __forceinline__ float wsum(float v) {
#pragma unroll
    for (int m = 32; m; m >>= 1) v += __shfl_xor(v, m, 64);
    return v;
}

__device__ __forceinline__ float artanhf_(float x) {
    x = fminf(fmaxf(x, -1.0f + 1e-7f), 1.0f - 1e-7f);
    return 0.5f * logf((1.0f + x) / (1.0f - x));
}

// dot-4 of a float4 row chunk against 4 shuffled-broadcast components of v
#define MATVEC4(q, d0, v, acc)                                              \
    acc += (q).x * __shfl((v), (d0) + 0, 64)                                \
         + (q).y * __shfl((v), (d0) + 1, 64)                                \
         + (q).z * __shfl((v), (d0) + 2, 64)                                \
         + (q).w * __shfl((v), (d0) + 3, 64);

__global__ __launch_bounds__(256) void kg_agg_kernel(
    const float* __restrict__ self_v,   // (B,1,64)
    const float* __restrict__ user_v,   // (B,16,64)
    const float* __restrict__ ent_v,    // (B,1,16,64)
    const float* __restrict__ item_e,   // (B,64)
    const float* __restrict__ Wr,       // (B,1,16,64,64)
    const float* __restrict__ Wui,      // (64,64)
    const float* __restrict__ linW,     // (64,64)
    const float* __restrict__ linb,     // (64,)
    float* __restrict__ out)            // (B,1,64) fp32
{
    __shared__ float sE[1024];    // E tile
    __shared__ float stself[64];  // logmap0(self)
    __shared__ float sRaw[16];    // bilinear-form raw logits

    const int b    = blockIdx.x;
    const int tid  = threadIdx.x;
    const int lane = tid & 63;
    const int wv   = tid >> 6;

    // ---- stage E (coalesced, all 256 threads) ----
    for (int i = tid; i < 1024; i += 256)
        sE[i] = ent_v[(size_t)b * 1024 + i];

    // ---- wave 0: t_self ----
    float xl = 0.f, x2 = 0.f;
    if (wv == 0) {
        xl = self_v[(size_t)b * 64 + lane];
        x2 = wsum(xl * xl);
        float xn = fmaxf(sqrtf(x2), MINV);
        stself[lane] = artanhf_(xn) / xn * xl;
    }
    __syncthreads();

    // ---- phase B: stream Wr (512 MB total), bilinear logits. 4 waves x 4 s ----
    {
        const float4* wp = (const float4*)(Wr + (size_t)b * 65536);
        for (int s = wv; s < 16; s += 4) {
            const float4* sp = wp + s * 1024;  // 4096 floats per s
            float acc = 0.f;
#pragma unroll
            for (int j = 0; j < 16; ++j) {
                float4 q = sp[j * 64 + lane];     // flat float idx = j*256 + lane*4
                int r  = j * 4 + (lane >> 4);     // row index
                int c0 = (lane & 15) * 4;         // col chunk start
                float er = sE[s * 64 + r];
                float dp = q.x * stself[c0 + 0] + q.y * stself[c0 + 1]
                         + q.z * stself[c0 + 2] + q.w * stself[c0 + 3];
                acc += er * dp;
            }
            acc = wsum(acc);
            if (lane == 0) sRaw[s] = acc;
        }
    }
    __syncthreads();
    if (wv != 0) return;   // waves 1-3 done; no more barriers below

    // ================= wave 0: all the small vector math =================
    // ---- KG attention softmax ----
    float att[16];
    float mxl = -1e30f;
    for (int s = 0; s < 16; ++s) {
        float el = sE[s * 64 + lane];
        float e2 = wsum(el * el);
        float en = fmaxf(sqrtf(e2), MINV);
        float lg = artanhf_(en) / en * sRaw[s];
        att[s] = lg;
        mxl = fmaxf(mxl, lg);
    }
    float ssum = 0.f;
    for (int s = 0; s < 16; ++s) { att[s] = expf(att[s] - mxl); ssum += att[s]; }
    float sinv = 1.f / ssum;

    // ---- KG aggregation: sum_s att*logmap(x, E_s), then expmap at x ----
    float lam  = fmaxf(2.f / (1.f - x2), MINV);
    float aggl = 0.f;
    for (int s = 0; s < 16; ++s) {
        float el  = sE[s * 64 + lane];
        float e2  = wsum(el * el);
        float dxe = wsum(xl * el);
        float den = fmaxf(1.f - 2.f * dxe + x2 * e2, MINV);
        float subl = ((1.f - 2.f * dxe + e2) * (-xl) + (1.f - x2) * el) / den;
        float sn = fmaxf(sqrtf(wsum(subl * subl)), MINV);
        float coeff = (2.f / lam) * artanhf_(sn) / sn;
        aggl += (att[s] * sinv) * coeff * subl;
    }
    float un   = fmaxf(sqrtf(wsum(aggl * aggl)), MINV);
    float secl = tanhf(lam * un * 0.5f) * aggl / un;
    float ss2  = wsum(secl * secl);
    float xss  = wsum(xl * secl);
    float kgl  = ((1.f + 2.f * xss + ss2) * xl + (1.f - x2) * secl)
               / fmaxf(1.f + 2.f * xss + x2 * ss2, MINV);

    // ---- user branch ----
    float ivl = item_e[(size_t)b * 64 + lane];
    float i2  = wsum(ivl * ivl);
    float inn = fmaxf(sqrtf(i2), MINV);
    float til = artanhf_(inn) / inn * ivl;   // t_item component

    // imW[lane] = sum_d t_item[d] * Wui[lane][d]
    float imw = 0.f;
    {
        const float4* wq = (const float4*)Wui;
#pragma unroll
        for (int j = 0; j < 16; ++j) {
            float4 q = wq[lane * 16 + j];
            MATVEC4(q, j * 4, til, imw)
        }
    }

    const float* ub = user_v + (size_t)b * 1024;
    float uatt[16];
    float umx = -1e30f;
    for (int s = 0; s < 16; ++s) {
        float ul = ub[s * 64 + lane];
        float u2 = wsum(ul * ul);
        float unr = fmaxf(sqrtf(u2), MINV);
        float lg  = artanhf_(unr) / unr * wsum(imw * ul);
        uatt[s] = lg;
        umx = fmaxf(umx, lg);
    }
    float usum = 0.f;
    for (int s = 0; s < 16; ++s) { uatt[s] = expf(uatt[s] - umx); usum += uatt[s]; }
    float uinv = 1.f / usum;

    float lami  = fmaxf(2.f / (1.f - i2), MINV);
    float uaggl = 0.f;
    for (int s = 0; s < 16; ++s) {
        float ul  = ub[s * 64 + lane];
        float u2  = wsum(ul * ul);
        float dxy = wsum(ivl * ul);
        float den = fmaxf(1.f - 2.f * dxy + i2 * u2, MINV);
        float subl = ((1.f - 2.f * dxy + u2) * (-ivl) + (1.f - i2) * ul) / den;
        float sn = fmaxf(sqrtf(wsum(subl * subl)), MINV);
        float coeff = (2.f / lami) * artanhf_(sn) / sn;
        uaggl += (uatt[s] * uinv) * coeff * subl;
    }
    float uun  = fmaxf(sqrtf(wsum(uaggl * uaggl)), MINV);
    float usec = tanhf(lami * uun * 0.5f) * uaggl / uun;
    float us2  = wsum(usec * usec);
    float uxs  = wsum(ivl * usec);
    float ual  = ((1.f + 2.f * uxs + us2) * ivl + (1.f - i2) * usec)
               / fmaxf(1.f + 2.f * uxs + i2 * us2, MINV);

    // ---- combine: mobius_add(mobius_add(x, kg), user) ----
    float k2 = wsum(kgl * kgl), xk = wsum(xl * kgl);
    float o1 = ((1.f + 2.f * xk + k2) * xl + (1.f - x2) * kgl)
             / fmaxf(1.f + 2.f * xk + x2 * k2, MINV);
    float o12 = wsum(o1 * o1), ua2 = wsum(ual * ual), o1u = wsum(o1 * ual);
    float v   = ((1.f + 2.f * o1u + ua2) * o1 + (1.f - o12) * ual)
              / fmaxf(1.f + 2.f * o1u + o12 * ua2, MINV);

    // ---- hyp_linear ----
    float v2 = wsum(v * v);
    float vn = fmaxf(sqrtf(v2), MINV);
    float mxv = 0.f;
    {
        const float4* wq = (const float4*)linW;
#pragma unroll
        for (int j = 0; j < 16; ++j) {
            float4 q = wq[lane * 16 + j];
            MATVEC4(q, j * 4, v, mxv)
        }
    }
    float mxn = fmaxf(sqrtf(wsum(mxv * mxv)), MINV);
    float res = tanhf(mxn / vn * artanhf_(vn)) * mxv / mxn;
    if (__ballot(mxv != 0.f) == 0ull) res = 0.f;   // all(mx==0) guard
    float rn = fmaxf(sqrtf(wsum(res * res)), MINV);
    if (rn > MAXNRM) res = res / rn * MAXNRM;

    float bl = linb[lane];
    float bn = fmaxf(sqrtf(wsum(bl * bl)), MINV);
    float hb = tanhf(bn) * bl / bn;
    float hn = fmaxf(sqrtf(wsum(hb * hb)), MINV);
    if (hn > MAXNRM) hb = hb / hn * MAXNRM;

    float r2 = wsum(res * res), h2 = wsum(hb * hb), rh = wsum(res * hb);
    float o3 = ((1.f + 2.f * rh + h2) * res + (1.f - r2) * hb)
             / fmaxf(1.f + 2.f * rh + r2 * h2, MINV);
    float on = fmaxf(sqrtf(wsum(o3 * o3)), MINV);
    if (on > MAXNRM) o3 = o3 / on * MAXNRM;

    // ---- final: expmap0(tanh(logmap0(o3))) ----
    float on2 = fmaxf(sqrtf(wsum(o3 * o3)), MINV);
    float tl  = tanhf(artanhf_(on2) / on2 * o3);
    float tn  = fmaxf(sqrtf(wsum(tl * tl)), MINV);
    float outl = tanhf(tn) * tl / tn;

    out[(size_t)b * 64 + lane] = outl;
}

extern "C" void kernel_launch(void* const* d_in, const int* in_sizes, int n_in,
                              void* d_out, int out_size, void* d_ws, size_t ws_size,
                              hipStream_t stream) {
    const float* self_v = (const float*)d_in[0];
    const float* user_v = (const float*)d_in[1];
    const float* ent_v  = (const float*)d_in[2];
    const float* item_e = (const float*)d_in[3];
    const float* Wr     = (const float*)d_in[4];
    const float* Wui    = (const float*)d_in[5];
    const float* linW   = (const float*)d_in[6];
    const float* linb   = (const float*)d_in[7];
    float* out = (float*)d_out;

    const int B = in_sizes[0] / 64;   // 2048
    kg_agg_kernel<<<B, 256, 0, stream>>>(self_v, user_v, ent_v, item_e,
                                         Wr, Wui, linW, linb, out);
}